// Round 6
// baseline (348.300 us; speedup 1.0000x reference)
//
#include <hip/hip_runtime.h>

#define SEQ 1024
#define BATCH 512
#define NTAGS 64
#define HALF_T 512
#define LOGD 4.158883083f   // log(64): per-step damp folded into exp(em)

typedef _Float16 v2h __attribute__((ext_vector_type(2)));

// Compiler-only ordering fence: single-wave lockstep + in-order DS pipe means
// no s_barrier is needed, just stop compiler reordering around LDS ops.
#define FENCE() asm volatile("" ::: "memory")

__device__ __forceinline__ float dot2acc(v2h a, v2h b, float c) {
#if __has_builtin(__builtin_amdgcn_fdot2)
    return __builtin_amdgcn_fdot2(a, b, c, false);
#else
    return fmaf((float)a.x, (float)b.x, fmaf((float)a.y, (float)b.y, c));
#endif
}

__device__ __forceinline__ float rfl(float x) {
    return __uint_as_float(__builtin_amdgcn_readfirstlane(__float_as_uint(x)));
}

// Scan: block < BATCH -> forward chain b over t=1..min(L-1,511);
//       block >= BATCH -> backward chain b over t=L-1..512 (descending).
// Linear space, per-step damp 1/64, renorm every 4 steps by r=rfl(dot).
// Numerator FUSED (R2 recipe): wave-uniform tags loads (prefetch dist 4),
// trans from LDS, em gather = one shfl of the resident em register; all
// issued after the group's DOTs so the DS pipe serves the recurrence first.
__global__ __launch_bounds__(64)
void scan_kernel(const float* __restrict__ em,
                 const int* __restrict__ tags,
                 const int* __restrict__ mask,
                 const float* __restrict__ startT,
                 const float* __restrict__ endT,
                 const float* __restrict__ trans,
                 float* __restrict__ beta_f, float* __restrict__ Mf,
                 float* __restrict__ gma,    float* __restrict__ Mb,
                 float* __restrict__ out)
{
    const bool fwd = blockIdx.x < BATCH;
    const int  b   = fwd ? blockIdx.x : blockIdx.x - BATCH;
    const int  j   = threadIdx.x;

    __shared__ __align__(16) _Float16 bsh[NTAGS];
    __shared__ float tr_sh[NTAGS * NTAGS];

    // raw trans into LDS for numerator lookups (coalesced, startup only)
#pragma unroll
    for (int i = 0; i < NTAGS; ++i)
        tr_sh[i * NTAGS + j] = trans[i * NTAGS + j];

    // chain length = sum of (prefix) mask column
    int lsum = 0;
#pragma unroll
    for (int k = 0; k < SEQ / 64; ++k)
        lsum += mask[(k * 64 + j) * BATCH + b];
#pragma unroll
    for (int off = 32; off > 0; off >>= 1)
        lsum += __shfl_xor(lsum, off);
    const int L = lsum;

    // fp16 expT fragment: fwd lane j = column j (paired over i);
    // bwd lane j = row j (paired over k).
    v2h w[32];
#pragma unroll
    for (int i = 0; i < 32; ++i) {
        float a0, a1;
        if (fwd) { a0 = trans[(2 * i) * NTAGS + j]; a1 = trans[(2 * i + 1) * NTAGS + j]; }
        else     { a0 = trans[j * NTAGS + 2 * i];   a1 = trans[j * NTAGS + 2 * i + 1];   }
        v2h t; t.x = (_Float16)__expf(a0); t.y = (_Float16)__expf(a1);
        w[i] = t;
    }
    FENCE();  // tr_sh written (single wave, in-order DS)

    const float4* bv = (const float4*)bsh;

    // 8 accumulators: dep chains 4 deep per accumulator
#define DOT(WRVAL, SOUT)                                                   \
    {                                                                      \
        FENCE();                                                           \
        bsh[j] = (_Float16)(WRVAL);                                        \
        FENCE();                                                           \
        float a0=0.f,a1=0.f,a2=0.f,a3=0.f,a4=0.f,a5=0.f,a6=0.f,a7=0.f;     \
        _Pragma("unroll")                                                  \
        for (int q4 = 0; q4 < 8; q4 += 2) {                                \
            float4 qa = bv[q4], qb = bv[q4 + 1];                           \
            a0 = dot2acc(__builtin_bit_cast(v2h, qa.x), w[4 * q4 + 0], a0);\
            a1 = dot2acc(__builtin_bit_cast(v2h, qa.y), w[4 * q4 + 1], a1);\
            a2 = dot2acc(__builtin_bit_cast(v2h, qa.z), w[4 * q4 + 2], a2);\
            a3 = dot2acc(__builtin_bit_cast(v2h, qa.w), w[4 * q4 + 3], a3);\
            a4 = dot2acc(__builtin_bit_cast(v2h, qb.x), w[4 * q4 + 4], a4);\
            a5 = dot2acc(__builtin_bit_cast(v2h, qb.y), w[4 * q4 + 5], a5);\
            a6 = dot2acc(__builtin_bit_cast(v2h, qb.z), w[4 * q4 + 6], a6);\
            a7 = dot2acc(__builtin_bit_cast(v2h, qb.w), w[4 * q4 + 7], a7);\
        }                                                                  \
        SOUT = ((a0 + a4) + (a1 + a5)) + ((a2 + a6) + (a3 + a7));          \
    }

    float num = 0.0f;

    if (fwd) {
        float em0 = em[(size_t)b * NTAGS + j];
        float a0  = startT[j] + em0;
        float M    = __shfl(a0, 0);
        float beta = __expf(a0 - M);
        int nsteps = 0;

        int t0 = tags[b];
        num = startT[t0] + __shfl(em0, t0);
        if (L <= HALF_T)
            num += endT[tags[(size_t)(L - 1) * BATCH + b]];

        const int Lf = min(L - 1, HALF_T - 1);   // active steps t=1..Lf
        int t = 1;
        float cur[4], nxt[4]; int tgc[4], tgn[4];
#pragma unroll
        for (int u = 0; u < 4; ++u) {
            int ta = min(t + u, SEQ - 1), tb = min(t + 4 + u, SEQ - 1);
            cur[u] = em[((size_t)ta * BATCH + b) * NTAGS + j];
            nxt[u] = em[((size_t)tb * BATCH + b) * NTAGS + j];
            tgc[u] = tags[ta * BATCH + b];
            tgn[u] = tags[tb * BATCH + b];
        }
        int prev = t0;

        while (t + 3 <= Lf) {
            float pre[4]; int tgp[4];
#pragma unroll
            for (int u = 0; u < 4; ++u) {
                int tp = min(t + 8 + u, SEQ - 1);
                pre[u] = em[((size_t)tp * BATCH + b) * NTAGS + j];
                tgp[u] = tags[tp * BATCH + b];
            }
            float eem[4];
#pragma unroll
            for (int u = 0; u < 4; ++u) eem[u] = __expf(cur[u] - LOGD);

            float s;
            DOT(beta, s); beta = s * eem[0];
            DOT(beta, s);
            float r = rfl(s);
            beta = s * eem[1];
            DOT(beta, s); beta = s * eem[2];
            float rinv = 1.0f / r;           // off-path
            float lr   = __logf(r);          // off-path
            DOT(beta, s); beta = s * (eem[3] * rinv);
            M += lr;
            nsteps += 4;

            // numerator (after DOTs: DS pipe served the recurrence first)
            num += tr_sh[prev   * NTAGS + tgc[0]] + __shfl(cur[0], tgc[0]);
            num += tr_sh[tgc[0] * NTAGS + tgc[1]] + __shfl(cur[1], tgc[1]);
            num += tr_sh[tgc[1] * NTAGS + tgc[2]] + __shfl(cur[2], tgc[2]);
            num += tr_sh[tgc[2] * NTAGS + tgc[3]] + __shfl(cur[3], tgc[3]);
            prev = tgc[3];

#pragma unroll
            for (int u = 0; u < 4; ++u) {
                cur[u] = nxt[u]; nxt[u] = pre[u];
                tgc[u] = tgn[u]; tgn[u] = tgp[u];
            }
            t += 4;
        }
        for (; t <= Lf; ++t) {
            float emt = em[((size_t)t * BATCH + b) * NTAGS + j];
            int   ct  = tags[t * BATCH + b];
            num += tr_sh[prev * NTAGS + ct] + __shfl(emt, ct);
            prev = ct;
            float s; DOT(beta, s);
            beta = s * __expf(emt - LOGD);
            ++nsteps;
        }

        beta_f[b * NTAGS + j] = beta;
        if (j == 0) {
            Mf[b] = fmaf((float)nsteps, LOGD, M);
            atomicAdd(out, num);
        }
    } else {
        float beta = __expf(endT[j]);        // B_j init (value at t = L-1)
        float M = 0.0f;
        int nsteps = 0;

        if (L - 1 >= HALF_T) {
            int tt = L - 1;                  // steps tt = L-1 .. 512 descending
            float cur[4], nxt[4]; int tgc[4], tgn[4];
#pragma unroll
            for (int u = 0; u < 4; ++u) {
                int ta = max(tt - u, 0), tb = max(tt - 4 - u, 0);
                cur[u] = em[((size_t)ta * BATCH + b) * NTAGS + j];
                nxt[u] = em[((size_t)tb * BATCH + b) * NTAGS + j];
                tgc[u] = tags[ta * BATCH + b];
                tgn[u] = tags[tb * BATCH + b];
            }
            num = endT[tgc[0]];              // end term (L > 512 owner)

            while (tt - 3 >= HALF_T) {
                float pre[4]; int tgp[4];
#pragma unroll
                for (int u = 0; u < 4; ++u) {
                    int tp = max(tt - 8 - u, 0);
                    pre[u] = em[((size_t)tp * BATCH + b) * NTAGS + j];
                    tgp[u] = tags[tp * BATCH + b];
                }
                float eem[4];
#pragma unroll
                for (int u = 0; u < 4; ++u) eem[u] = __expf(cur[u] - LOGD);

                float s;
                DOT(beta * eem[0], s); beta = s;
                DOT(beta * eem[1], s);
                float r = rfl(s);
                beta = s;
                DOT(beta * eem[2], s); beta = s;
                float rinv = 1.0f / r;
                float lr   = __logf(r);
                DOT(beta * (eem[3] * rinv), s); beta = s;
                M += lr;
                nsteps += 4;

                // numerator: term at time tt-u uses (tags[tt-u-1], tags[tt-u])
                num += tr_sh[tgc[1] * NTAGS + tgc[0]] + __shfl(cur[0], tgc[0]);
                num += tr_sh[tgc[2] * NTAGS + tgc[1]] + __shfl(cur[1], tgc[1]);
                num += tr_sh[tgc[3] * NTAGS + tgc[2]] + __shfl(cur[2], tgc[2]);
                num += tr_sh[tgn[0] * NTAGS + tgc[3]] + __shfl(cur[3], tgc[3]);

#pragma unroll
                for (int u = 0; u < 4; ++u) {
                    cur[u] = nxt[u]; nxt[u] = pre[u];
                    tgc[u] = tgn[u]; tgn[u] = tgp[u];
                }
                tt -= 4;
            }
            for (; tt >= HALF_T; --tt) {
                float emt = em[((size_t)tt * BATCH + b) * NTAGS + j];
                int   ct  = tags[tt * BATCH + b];
                int   pt  = tags[(tt - 1) * BATCH + b];
                num += tr_sh[pt * NTAGS + ct] + __shfl(emt, ct);
                float s; DOT(beta * __expf(emt - LOGD), s);
                beta = s;
                ++nsteps;
            }
        }
        gma[b * NTAGS + j] = beta;
        if (j == 0) {
            Mb[b] = fmaf((float)nsteps, LOGD, M);
            atomicAdd(out, num);
        }
    }
#undef DOT
}

// Join: midpoint dot only -> denominator; subtract from out.
__global__ __launch_bounds__(64)
void join_kernel(const float* __restrict__ beta_f, const float* __restrict__ Mf,
                 const float* __restrict__ gma,    const float* __restrict__ Mb,
                 float* __restrict__ out)
{
    const int b = blockIdx.x;
    const int j = threadIdx.x;
    float p = beta_f[b * NTAGS + j] * gma[b * NTAGS + j];
#pragma unroll
    for (int off = 32; off > 0; off >>= 1)
        p += __shfl_xor(p, off);
    if (j == 0)
        atomicAdd(out, -(__logf(p) + Mf[b] + Mb[b]));
}

extern "C" void kernel_launch(void* const* d_in, const int* in_sizes, int n_in,
                              void* d_out, int out_size, void* d_ws, size_t ws_size,
                              hipStream_t stream)
{
    const float* em     = (const float*)d_in[0];
    const int*   tags   = (const int*)d_in[1];
    const int*   mask   = (const int*)d_in[2];
    const float* startT = (const float*)d_in[3];
    const float* endT   = (const float*)d_in[4];
    const float* trans  = (const float*)d_in[5];
    float*       out    = (float*)d_out;

    float* beta_f = (float*)d_ws;                 // 512*64
    float* Mf     = beta_f + BATCH * NTAGS;       // 512
    float* gma    = Mf + BATCH;                   // 512*64
    float* Mb     = gma + BATCH * NTAGS;          // 512

    hipMemsetAsync(out, 0, sizeof(float) * out_size, stream);
    scan_kernel<<<2 * BATCH, 64, 0, stream>>>(em, tags, mask, startT, endT, trans,
                                              beta_f, Mf, gma, Mb, out);
    join_kernel<<<BATCH, 64, 0, stream>>>(beta_f, Mf, gma, Mb, out);
}